// Round 7
// baseline (303.854 us; speedup 1.0000x reference)
//
#include <hip/hip_runtime.h>
#include <hip/hip_bf16.h>
#include <cstdint>
#include <cstddef>

// Problem constants
constexpr int T_Q   = 32400;   // BEV queries
constexpr int T_PAD = 32512;   // padded (multiple of 32)
constexpr int S_K   = 16896;   // feature keys
constexpr int E_DIM = 256;
constexpr int HID   = 512;

typedef __bf16 bf16x8 __attribute__((ext_vector_type(8)));
typedef float  f32x4  __attribute__((ext_vector_type(4)));
typedef unsigned short ushort8v __attribute__((ext_vector_type(8)));

__device__ __forceinline__ void async16(const void* gp, void* lp) {
    __builtin_amdgcn_global_load_lds(
        (const __attribute__((address_space(1))) void*)(gp),
        (__attribute__((address_space(3))) void*)(lp), 16, 0, 0);
}

__device__ __forceinline__ float b2f(unsigned short u) {
    return __uint_as_float(((unsigned)u) << 16);
}

// ---------------------------------------------------------------------------
// prep: weight transpose to [N][K] bf16 via LDS tiles (128 blocks).
__global__ __launch_bounds__(256) void prep(
    const float* __restrict__ s0, const float* __restrict__ s1,
    const float* __restrict__ s2, const float* __restrict__ s3,
    __hip_bfloat16* __restrict__ d0, __hip_bfloat16* __restrict__ d1,
    __hip_bfloat16* __restrict__ d2, __hip_bfloat16* __restrict__ d3) {
    __shared__ float tb[64][65];
    const int tid = threadIdx.x;
    int m = blockIdx.x >> 5;
    int tt = blockIdx.x & 31;
    const float* S = m == 0 ? s0 : m == 1 ? s1 : m == 2 ? s2 : s3;
    __hip_bfloat16* D = m == 0 ? d0 : m == 1 ? d1 : m == 2 ? d2 : d3;
    int Kd, Nd, kt, nt;
    if ((m & 1) == 0) { Kd = 256; Nd = 512; kt = tt & 3; nt = tt >> 2; }
    else              { Kd = 512; Nd = 256; kt = tt & 7; nt = tt >> 3; }
    int tx = tid & 63, ty = tid >> 6;
#pragma unroll
    for (int p = 0; p < 16; ++p) {
        int row = ty * 16 + p;
        tb[row][tx] = S[(size_t)(kt * 64 + row) * Nd + nt * 64 + tx];
    }
    __syncthreads();
#pragma unroll
    for (int p = 0; p < 16; ++p) {
        int row = ty * 16 + p;
        D[(size_t)(nt * 64 + row) * Kd + kt * 64 + tx] = __float2bfloat16(tb[tx][row]);
    }
}

// ---------------------------------------------------------------------------
// gemm1: BM=32, BN=512 (full), BK=32, fused fp32->bf16 A-cast, relu, dual q/k.
// A read exactly once from HBM; B (w1T, 256 KB) restaged from L2 each iter.
__global__ __launch_bounds__(256) void gemm1(
    const float* __restrict__ Aq, const float* __restrict__ Ak,
    const __hip_bfloat16* __restrict__ BTq, const __hip_bfloat16* __restrict__ BTk,
    const float* __restrict__ biasq, const float* __restrict__ biask,
    __hip_bfloat16* __restrict__ Cq, __hip_bfloat16* __restrict__ Ck,
    int qtiles) {
    __shared__ __hip_bfloat16 As[32 * 32];    // 2 KB
    __shared__ __hip_bfloat16 Bs[512 * 32];   // 32 KB

    const int tm = blockIdx.x;
    const bool isq = tm < qtiles;
    const float* A  = isq ? Aq : Ak;
    const __hip_bfloat16* BT = isq ? BTq : BTk;
    const float* bias = isq ? biasq : biask;
    __hip_bfloat16* C = isq ? Cq : Ck;
    const int mrow0 = (isq ? tm : tm - qtiles) * 32;
    const int rowlim = isq ? T_Q : S_K;

    const int tid = threadIdx.x;
    const int w = tid >> 6, l = tid & 63;
    const int lm = l & 15, lq = l >> 4;
    const int wn = w * 128;

    // B staging lane geometry: 16 rows/instr, lane -> row l>>2, unit l&3
    const int brow = l >> 2;
    const int bu   = ((l & 3) ^ (brow & 3)) << 3;   // logical elem col (swizzled)
    // A staging: thread t handles 4 elems: row t>>3, quad t&7
    const int ar = tid >> 3, aq4 = tid & 7;
    const int aphys = (((aq4 >> 1) ^ (ar & 3)) << 4) + (aq4 & 1) * 8; // byte off in row

    f32x4 acc[2][8] = {};

    for (int k0 = 0; k0 < 256; k0 += 32) {
        // stage A (fp32 -> bf16 -> LDS)
        {
            int gr = mrow0 + ar;
            float4 f = make_float4(0.f, 0.f, 0.f, 0.f);
            if (gr < rowlim) f = *(const float4*)(A + (size_t)gr * 256 + k0 + aq4 * 4);
            union { ushort4 u4; __hip_bfloat16 bb[4]; } cv;
            cv.bb[0] = __float2bfloat16(f.x);
            cv.bb[1] = __float2bfloat16(f.y);
            cv.bb[2] = __float2bfloat16(f.z);
            cv.bb[3] = __float2bfloat16(f.w);
            *(ushort4*)((char*)As + ar * 64 + aphys) = cv.u4;
        }
        // stage B: 512 rows x 64B; wave w covers chunks w*8..w*8+7
#pragma unroll
        for (int j = 0; j < 8; ++j) {
            int c = w * 8 + j;
            int n = 16 * c + brow;
            async16(BT + (size_t)n * 256 + k0 + bu, Bs + 16 * c * 32);
        }
        __syncthreads();

        bf16x8 af[2], bfr[8];
#pragma unroll
        for (int mi = 0; mi < 2; ++mi) {
            int row = mi * 16 + lm;
            int pu = lq ^ (row & 3);
            af[mi] = *(const bf16x8*)(As + row * 32 + pu * 8);
        }
#pragma unroll
        for (int ni = 0; ni < 8; ++ni) {
            int row = wn + ni * 16 + lm;
            int pu = lq ^ (row & 3);
            bfr[ni] = *(const bf16x8*)(Bs + row * 32 + pu * 8);
        }
#pragma unroll
        for (int mi = 0; mi < 2; ++mi)
#pragma unroll
            for (int ni = 0; ni < 8; ++ni)
                acc[mi][ni] = __builtin_amdgcn_mfma_f32_16x16x32_bf16(
                    af[mi], bfr[ni], acc[mi][ni], 0, 0, 0);
        __syncthreads();
    }

#pragma unroll
    for (int ni = 0; ni < 8; ++ni) {
        int col = wn + ni * 16 + lm;
        float bv = bias[col];
#pragma unroll
        for (int mi = 0; mi < 2; ++mi) {
            size_t rowb = (size_t)mrow0 + mi * 16 + lq * 4;
#pragma unroll
            for (int r = 0; r < 4; ++r) {
                float vv = fmaxf(acc[mi][ni][r] + bv, 0.f);
                C[(rowb + r) * HID + col] = __float2bfloat16(vv);
            }
        }
    }
}

// ---------------------------------------------------------------------------
// gemm2: BM=32, BN=256 (full), BK=64, A bf16 via async16, dual q/k,
// k-side fuses the v fp32->bf16 cast into kv cols 256..511.
__global__ __launch_bounds__(256) void gemm2(
    const __hip_bfloat16* __restrict__ Aq, const __hip_bfloat16* __restrict__ Ak,
    const __hip_bfloat16* __restrict__ BTq, const __hip_bfloat16* __restrict__ BTk,
    const float* __restrict__ biasq, const float* __restrict__ biask,
    __hip_bfloat16* __restrict__ Cq, __hip_bfloat16* __restrict__ Ck,
    const float* __restrict__ val_in,
    float scaleq, int qtiles) {
    __shared__ __hip_bfloat16 As[32 * 64];    // 4 KB
    __shared__ __hip_bfloat16 Bs[256 * 64];   // 32 KB

    const int tm = blockIdx.x;
    const bool isq = tm < qtiles;
    const __hip_bfloat16* A  = isq ? Aq : Ak;
    const __hip_bfloat16* BT = isq ? BTq : BTk;
    const float* bias = isq ? biasq : biask;
    __hip_bfloat16* C = isq ? Cq : Ck;
    const int ldc = isq ? E_DIM : 512;
    const float scale = isq ? scaleq : 1.0f;
    const int mrow0 = (isq ? tm : tm - qtiles) * 32;

    const int tid = threadIdx.x;
    const int w = tid >> 6, l = tid & 63;
    const int lm = l & 15, lq = l >> 4;
    const int wn = w * 64;

    const int srow = l >> 3;                      // 0..7
    const int su   = ((l & 7) ^ srow) << 3;       // swizzled elem col

    f32x4 acc[2][4] = {};

    for (int k0 = 0; k0 < 512; k0 += 64) {
        // stage A: 32 rows x 128B; wave w covers rows 8w..8w+7
        {
            int row = 8 * w + srow;
            async16(A + (size_t)(mrow0 + row) * 512 + k0 + su, As + 8 * w * 64);
        }
        // stage B: 256 rows x 128B; wave w chunks w*8..w*8+7 (8 rows each)
#pragma unroll
        for (int j = 0; j < 8; ++j) {
            int c = w * 8 + j;
            int n = 8 * c + srow;
            async16(BT + (size_t)n * 512 + k0 + su, Bs + 8 * c * 64);
        }
        __syncthreads();

#pragma unroll
        for (int ks = 0; ks < 2; ++ks) {
            bf16x8 af[2], bfr[4];
#pragma unroll
            for (int mi = 0; mi < 2; ++mi) {
                int row = mi * 16 + lm;
                int pu = (ks * 4 + lq) ^ (row & 7);
                af[mi] = *(const bf16x8*)(As + row * 64 + pu * 8);
            }
#pragma unroll
            for (int ni = 0; ni < 4; ++ni) {
                int row = wn + ni * 16 + lm;
                int pu = (ks * 4 + lq) ^ (row & 7);
                bfr[ni] = *(const bf16x8*)(Bs + row * 64 + pu * 8);
            }
#pragma unroll
            for (int mi = 0; mi < 2; ++mi)
#pragma unroll
                for (int ni = 0; ni < 4; ++ni)
                    acc[mi][ni] = __builtin_amdgcn_mfma_f32_16x16x32_bf16(
                        af[mi], bfr[ni], acc[mi][ni], 0, 0, 0);
        }
        __syncthreads();
    }

#pragma unroll
    for (int ni = 0; ni < 4; ++ni) {
        int col = wn + ni * 16 + lm;
        float bv = bias[col];
#pragma unroll
        for (int mi = 0; mi < 2; ++mi) {
            size_t rowb = (size_t)mrow0 + mi * 16 + lq * 4;
#pragma unroll
            for (int r = 0; r < 4; ++r) {
                float vv = (acc[mi][ni][r] + bv) * scale;
                C[(rowb + r) * ldc + col] = __float2bfloat16(vv);
            }
        }
    }

    // fused v-cast for k tiles: 32 rows x 256 cols fp32 -> kv cols 256..511
    if (!isq) {
#pragma unroll
        for (int j = 0; j < 8; ++j) {
            int i4 = tid + j * 256;
            int row = i4 >> 6;
            int c4 = (i4 & 63) * 4;
            float4 f = *(const float4*)(val_in + (size_t)(mrow0 + row) * 256 + c4);
            union { ushort4 u4; __hip_bfloat16 bb[4]; } cv;
            cv.bb[0] = __float2bfloat16(f.x);
            cv.bb[1] = __float2bfloat16(f.y);
            cv.bb[2] = __float2bfloat16(f.z);
            cv.bb[3] = __float2bfloat16(f.w);
            *(ushort4*)(Ck + (size_t)(mrow0 + row) * 512 + 256 + c4) = cv.u4;
        }
    }
}

// ---------------------------------------------------------------------------
// Attention (R3 structure, non-online softmax): one wave per query, 2 points
// per chunk (half = l>>5 parity, sub = l&31 owns 16B of each 512B row),
// depth-3 register pipeline. Scores bounded (~|15|) -> exp without max.
#define APREF(DK, DV, C)                                                    \
    {                                                                       \
        int pidx = ((C) << 1) + half;                                       \
        int f = __builtin_amdgcn_ds_bpermute(pidx << 2, myf);               \
        const __hip_bfloat16* bp = kv + (size_t)f * 512 + sub * 8;          \
        DK = *(const ushort8v*)bp;                                          \
        DV = *(const ushort8v*)(bp + 256);                                  \
    }

#define APROC(KB, VB, C)                                                    \
    {                                                                       \
        float wv = 0.f;                                                     \
        _Pragma("unroll") for (int i = 0; i < 8; ++i)                       \
            wv = fmaf(qf[i], b2f(KB[i]), wv);                               \
        wv += __shfl_xor(wv, 1);                                            \
        wv += __shfl_xor(wv, 2);                                            \
        int pm = ((C) << 1) + half;                                         \
        if (pm >= L) wv = -1e30f;                                           \
        float p = __expf(wv);                                               \
        s += p;                                                             \
        _Pragma("unroll") for (int i = 0; i < 8; ++i)                       \
            a[i] = fmaf(p, b2f(VB[i]), a[i]);                               \
    }

__global__ __launch_bounds__(256) void attn_kernel(
    const __hip_bfloat16* __restrict__ q,
    const __hip_bfloat16* __restrict__ kv,
    const int* __restrict__ rf,
    const int* __restrict__ starts,
    const int* __restrict__ lens,
    float* __restrict__ out) {
    int t = blockIdx.x * 4 + (threadIdx.x >> 6);
    if (t >= T_Q) return;
    int l = threadIdx.x & 63;
    int half = l >> 5, sub = l & 31;
    int su = __builtin_amdgcn_readfirstlane(starts[t]);
    int L  = __builtin_amdgcn_readfirstlane(lens[t]);

    int li = l < L - 1 ? l : L - 1;
    int myf = rf[su + li];

    ushort8v qu = *(const ushort8v*)(q + (size_t)t * 256 + sub * 8);
    float qf[8];
#pragma unroll
    for (int i = 0; i < 8; ++i) qf[i] = b2f(qu[i]);

    float s = 0.f;
    float a[8] = {0.f, 0.f, 0.f, 0.f, 0.f, 0.f, 0.f, 0.f};

    ushort8v k0v = {}, v0v = {}, k1v = {}, v1v = {}, k2v = {}, v2v = {};

    int nC = (L + 1) >> 1;
    APREF(k0v, v0v, 0);
    if (nC > 1) APREF(k1v, v1v, 1);
    for (int c = 0; c < nC; ++c) {
        if (c + 2 < nC) APREF(k2v, v2v, c + 2);
        APROC(k0v, v0v, c);
        k0v = k1v; v0v = v1v;
        k1v = k2v; v1v = v2v;
    }

    s += __shfl_xor(s, 32);
#pragma unroll
    for (int i = 0; i < 8; ++i) a[i] += __shfl_xor(a[i], 32);
    float inv = 1.f / s;
    float4 o;
    o.x = (half ? a[4] : a[0]) * inv;
    o.y = (half ? a[5] : a[1]) * inv;
    o.z = (half ? a[6] : a[2]) * inv;
    o.w = (half ? a[7] : a[3]) * inv;
    *(float4*)(out + (size_t)t * 256 + sub * 8 + half * 4) = o;
}

// ---------------------------------------------------------------------------
extern "C" void kernel_launch(void* const* d_in, const int* in_sizes, int n_in,
                              void* d_out, int out_size, void* d_ws, size_t ws_size,
                              hipStream_t stream) {
    const float* q_in   = (const float*)d_in[0];
    const float* key_in = (const float*)d_in[1];
    const float* val_in = (const float*)d_in[2];
    const float* q_w1   = (const float*)d_in[3];
    const float* q_b1   = (const float*)d_in[4];
    const float* q_w2   = (const float*)d_in[5];
    const float* q_b2   = (const float*)d_in[6];
    const float* k_w1   = (const float*)d_in[7];
    const float* k_b1   = (const float*)d_in[8];
    const float* k_w2   = (const float*)d_in[9];
    const float* k_b2   = (const float*)d_in[10];
    const int* ranks_feat = (const int*)d_in[11];
    const int* starts     = (const int*)d_in[13];
    const int* lens       = (const int*)d_in[14];
    float* out = (float*)d_out;

    char* ws = (char*)d_ws;
    size_t off = 0;
    auto alloc = [&](size_t bytes) {
        char* p = ws + off;
        off += (bytes + 255) & ~(size_t)255;
        return p;
    };
    __hip_bfloat16* hidQ = (__hip_bfloat16*)alloc((size_t)T_PAD * HID * 2);
    __hip_bfloat16* hidK = (__hip_bfloat16*)alloc((size_t)S_K * HID * 2);
    __hip_bfloat16* qMl  = (__hip_bfloat16*)alloc((size_t)T_PAD * E_DIM * 2);
    __hip_bfloat16* kvB  = (__hip_bfloat16*)alloc((size_t)S_K * 512 * 2);
    __hip_bfloat16* w1qT = (__hip_bfloat16*)alloc((size_t)HID * E_DIM * 2);
    __hip_bfloat16* w2qT = (__hip_bfloat16*)alloc((size_t)E_DIM * HID * 2);
    __hip_bfloat16* w1kT = (__hip_bfloat16*)alloc((size_t)HID * E_DIM * 2);
    __hip_bfloat16* w2kT = (__hip_bfloat16*)alloc((size_t)E_DIM * HID * 2);
    (void)ws_size; (void)n_in; (void)out_size; (void)in_sizes;

    prep<<<128, 256, 0, stream>>>(q_w1, q_w2, k_w1, k_w2,
                                  w1qT, w2qT, w1kT, w2kT);

    const float qscale = 0.17677669529663687f;  // 1/sqrt(32)
    const int QT = T_PAD / 32;   // 1016
    const int KT = S_K / 32;     // 528

    gemm1<<<QT + KT, 256, 0, stream>>>(
        q_in, key_in, w1qT, w1kT, q_b1, k_b1, hidQ, hidK, QT);
    gemm2<<<QT + KT, 256, 0, stream>>>(
        hidQ, hidK, w2qT, w2kT, q_b2, k_b2, qMl, kvB, val_in, qscale, QT);

    attn_kernel<<<T_Q / 4, 256, 0, stream>>>(qMl, kvB, ranks_feat, starts, lens, out);
}